// Round 7
// baseline (486.498 us; speedup 1.0000x reference)
//
#include <hip/hip_runtime.h>
#include <hip/hip_bf16.h>
#include <cstdint>
#include <cstddef>

#define HID 128
#define SH 9                 // 512 nodes per bin
#define NODES_PER_BIN 512

typedef __attribute__((ext_vector_type(8))) __bf16 bf16x8;
typedef __attribute__((ext_vector_type(4))) float floatx4;

__device__ __forceinline__ ushort f2bf(float f) {
    uint u = __float_as_uint(f);
    u += 0x7fff + ((u >> 16) & 1);          // round-to-nearest-even
    return (ushort)(u >> 16);
}
__device__ __forceinline__ float bf2f(uint h) { return __uint_as_float(h << 16); }
__device__ __forceinline__ uint pack2(float a, float b) {
    return (uint)f2bf(a) | ((uint)f2bf(b) << 16);
}

// async global->LDS, 16B per lane; LDS dest is wave-uniform base + lane*16
__device__ __forceinline__ void async16(const ushort* g, ushort* l) {
    __builtin_amdgcn_global_load_lds(
        (const __attribute__((address_space(1))) uint*)g,
        (__attribute__((address_space(3))) uint*)l, 16, 0, 0);
}

// ============================ binned CSR build ============================

__global__ void k_hist(const int* __restrict__ dst, int E, int* __restrict__ binc) {
    __shared__ int h[256];
    int t = threadIdx.x;
    h[t] = 0;
    __syncthreads();
    for (int e = blockIdx.x * 256 + t; e < E; e += gridDim.x * 256)
        atomicAdd(&h[dst[e] >> SH], 1);
    __syncthreads();
    if (h[t]) atomicAdd(&binc[t], h[t]);
}

__global__ void k_binscan(const int* __restrict__ binc, int* __restrict__ bin_start,
                          int* __restrict__ bin_cursor, int E) {
    __shared__ int s[256];
    int t = threadIdx.x;
    int c = binc[t];
    s[t] = c;
    __syncthreads();
    #pragma unroll
    for (int off = 1; off < 256; off <<= 1) {
        int add = (t >= off) ? s[t - off] : 0;
        __syncthreads();
        s[t] += add;
        __syncthreads();
    }
    int excl = s[t] - c;
    bin_start[t] = excl;
    bin_cursor[t] = excl;
    if (t == 255) bin_start[256] = E;
}

// 2048 edges/block: in-LDS multi-split by bin, then coalesced bin-grouped writes.
// packed word = (d & 511) << 23 | src   (requires src < 2^23)
__global__ __launch_bounds__(256) void k_part(
    const int* __restrict__ src, const int* __restrict__ dst, int E,
    int* __restrict__ bin_cursor, uint* __restrict__ ebuf) {
    __shared__ int h[256];
    __shared__ int sc[256];
    __shared__ int rk[256];
    __shared__ int gb[256];
    __shared__ uint2 ro[2048];   // (d, packed)
    int t = threadIdx.x;
    int base = blockIdx.x * 2048;
    h[t] = 0;
    __syncthreads();
    int dd[8], ss[8];
    bool ok[8];
    #pragma unroll
    for (int k = 0; k < 8; ++k) {
        int e = base + k * 256 + t;
        ok[k] = e < E;
        if (ok[k]) {
            dd[k] = dst[e];
            ss[k] = src[e];
            atomicAdd(&h[dd[k] >> SH], 1);
        }
    }
    __syncthreads();
    sc[t] = h[t];
    __syncthreads();
    #pragma unroll
    for (int off = 1; off < 256; off <<= 1) {
        int add = (t >= off) ? sc[t - off] : 0;
        __syncthreads();
        sc[t] += add;
        __syncthreads();
    }
    rk[t] = sc[t] - h[t];           // exclusive
    {
        int c = h[t];
        if (c > 0) gb[t] = atomicAdd(&bin_cursor[t], c);
    }
    __syncthreads();
    #pragma unroll
    for (int k = 0; k < 8; ++k) {
        if (ok[k]) {
            int bin = dd[k] >> SH;
            int r = atomicAdd(&rk[bin], 1);
            ro[r] = make_uint2((uint)dd[k],
                               ((uint)(dd[k] & (NODES_PER_BIN - 1)) << 23) | (uint)ss[k]);
        }
    }
    __syncthreads();
    int nv = sc[255];
    for (int i = t; i < nv; i += 256) {
        uint2 pr = ro[i];
        int bin = (int)(pr.x >> SH);
        int excl = sc[bin] - h[bin];
        ebuf[gb[bin] + (i - excl)] = pr.y;
    }
}

// one block per bin: exact CSR for 512 nodes via LDS count+scan
__global__ __launch_bounds__(256) void k_csr(
    const uint* __restrict__ ebuf, const int* __restrict__ bin_start,
    int* __restrict__ rowptr, int* __restrict__ csr, int N, int E, int NB) {
    __shared__ int cnt[512];
    __shared__ int p[256];
    __shared__ int excl[512];
    int t = threadIdx.x;
    int b = blockIdx.x;
    int d0 = b << SH;
    int ebase = bin_start[b], eend = bin_start[b + 1];
    cnt[t] = 0; cnt[t + 256] = 0;
    __syncthreads();
    for (int e = ebase + t; e < eend; e += 256)
        atomicAdd(&cnt[ebuf[e] >> 23], 1);
    __syncthreads();
    p[t] = cnt[2 * t] + cnt[2 * t + 1];
    __syncthreads();
    #pragma unroll
    for (int off = 1; off < 256; off <<= 1) {
        int add = (t >= off) ? p[t - off] : 0;
        __syncthreads();
        p[t] += add;
        __syncthreads();
    }
    int e0 = (t == 0) ? 0 : p[t - 1];
    excl[2 * t] = e0;
    excl[2 * t + 1] = e0 + cnt[2 * t];
    __syncthreads();
    #pragma unroll
    for (int i = t; i < 512; i += 256) {
        int node = d0 + i;
        if (node < N) rowptr[node] = ebase + excl[i];
    }
    if (b == NB - 1 && t == 0) rowptr[N] = E;
    __syncthreads();
    for (int e = ebase + t; e < eend; e += 256) {
        uint w = ebuf[e];
        int r = atomicAdd(&excl[w >> 23], 1);
        csr[ebase + r] = (int)(w & 0x7FFFFFu);
    }
}

// ============================ prep: fp32 -> bf16, weight transposes ============

__global__ void k_cvt(const float* __restrict__ in, ushort* __restrict__ out, int n4) {
    int i = blockIdx.x * blockDim.x + threadIdx.x;
    if (i < n4) {
        float4 v = ((const float4*)in)[i];
        ((uint2*)out)[i] = make_uint2(pack2(v.x, v.y), pack2(v.z, v.w));
    }
}

__global__ void k_prepw(const float* __restrict__ Wl0, const float* __restrict__ Wr0,
                        const float* __restrict__ Wl1, const float* __restrict__ Wr1,
                        const float* __restrict__ W1,  const float* __restrict__ W2,
                        ushort* __restrict__ WlrT0, ushort* __restrict__ WlrT1,
                        ushort* __restrict__ W1T,   ushort* __restrict__ W2T) {
    int idx = blockIdx.x * 256 + threadIdx.x;
    if (idx < 32768) {
        int n = idx >> 8, k = idx & 255;
        float v = (k < 128) ? Wl0[k * 128 + n] : Wr0[(k - 128) * 128 + n];
        WlrT0[n * 256 + k] = f2bf(v);
    } else if (idx < 65536) {
        int t = idx - 32768; int n = t >> 8, k = t & 255;
        float v = (k < 128) ? Wl1[k * 128 + n] : Wr1[(k - 128) * 128 + n];
        WlrT1[n * 256 + k] = f2bf(v);
    } else if (idx < 98304) {
        int t = idx - 65536; int n = t >> 8, k = t & 255;
        W1T[n * 256 + k] = f2bf(W1[k * 128 + n]);
    } else if (idx < 100352) {
        int t = idx - 98304; int n = t >> 7, k = t & 127;
        W2T[n * 128 + k] = (n < 8) ? f2bf(W2[k * 8 + n]) : (ushort)0;
    }
}

// ============================ mean aggregation (bf16 in/out) ============================
// 16 lanes per node (quarter-wave owns the full 256 B row via uint4/lane);
// 4 nodes per wave, 16 per block. Edge loop unrolled x4 -> 4 gathers in flight.
__global__ __launch_bounds__(256) void k_agg4(const ushort* __restrict__ x,
                                              const int* __restrict__ rowptr,
                                              const int* __restrict__ csr,
                                              ushort* __restrict__ mean, int N) {
    int node = blockIdx.x * 16 + (threadIdx.x >> 4);
    if (node >= N) return;
    int u = threadIdx.x & 15;
    int b = rowptr[node], e = rowptr[node + 1];
    const uint4* xv = (const uint4*)x;      // row = 16 uint4
    float a0=0.f,a1=0.f,a2=0.f,a3=0.f,a4=0.f,a5=0.f,a6=0.f,a7=0.f;
    int j = b;
    for (; j + 3 < e; j += 4) {
        int s0 = csr[j], s1 = csr[j+1], s2 = csr[j+2], s3 = csr[j+3];
        uint4 v0 = xv[(size_t)s0 * 16 + u];
        uint4 v1 = xv[(size_t)s1 * 16 + u];
        uint4 v2 = xv[(size_t)s2 * 16 + u];
        uint4 v3 = xv[(size_t)s3 * 16 + u];
        a0 += __uint_as_float(v0.x << 16) + __uint_as_float(v1.x << 16)
            + __uint_as_float(v2.x << 16) + __uint_as_float(v3.x << 16);
        a1 += __uint_as_float(v0.x & 0xffff0000u) + __uint_as_float(v1.x & 0xffff0000u)
            + __uint_as_float(v2.x & 0xffff0000u) + __uint_as_float(v3.x & 0xffff0000u);
        a2 += __uint_as_float(v0.y << 16) + __uint_as_float(v1.y << 16)
            + __uint_as_float(v2.y << 16) + __uint_as_float(v3.y << 16);
        a3 += __uint_as_float(v0.y & 0xffff0000u) + __uint_as_float(v1.y & 0xffff0000u)
            + __uint_as_float(v2.y & 0xffff0000u) + __uint_as_float(v3.y & 0xffff0000u);
        a4 += __uint_as_float(v0.z << 16) + __uint_as_float(v1.z << 16)
            + __uint_as_float(v2.z << 16) + __uint_as_float(v3.z << 16);
        a5 += __uint_as_float(v0.z & 0xffff0000u) + __uint_as_float(v1.z & 0xffff0000u)
            + __uint_as_float(v2.z & 0xffff0000u) + __uint_as_float(v3.z & 0xffff0000u);
        a6 += __uint_as_float(v0.w << 16) + __uint_as_float(v1.w << 16)
            + __uint_as_float(v2.w << 16) + __uint_as_float(v3.w << 16);
        a7 += __uint_as_float(v0.w & 0xffff0000u) + __uint_as_float(v1.w & 0xffff0000u)
            + __uint_as_float(v2.w & 0xffff0000u) + __uint_as_float(v3.w & 0xffff0000u);
    }
    for (; j < e; ++j) {
        uint4 v = xv[(size_t)csr[j] * 16 + u];
        a0 += __uint_as_float(v.x << 16);
        a1 += __uint_as_float(v.x & 0xffff0000u);
        a2 += __uint_as_float(v.y << 16);
        a3 += __uint_as_float(v.y & 0xffff0000u);
        a4 += __uint_as_float(v.z << 16);
        a5 += __uint_as_float(v.z & 0xffff0000u);
        a6 += __uint_as_float(v.w << 16);
        a7 += __uint_as_float(v.w & 0xffff0000u);
    }
    float inv = 1.f / fmaxf((float)(e - b), 1.f);
    uint4 o;
    o.x = pack2(a0 * inv, a1 * inv);
    o.y = pack2(a2 * inv, a3 * inv);
    o.z = pack2(a4 * inv, a5 * inv);
    o.w = pack2(a6 * inv, a7 * inv);
    ((uint4*)mean)[(size_t)node * 16 + u] = o;
}

// ============================ layer GEMM (bf16 MFMA) ============================
__global__ __launch_bounds__(256) void k_gemm16(
    const ushort* __restrict__ Alo, const ushort* __restrict__ Ahi,
    const ushort* __restrict__ WT, const float* __restrict__ bias,
    ushort* __restrict__ out, int M) {
    __shared__ ushort As[4096];   // [128 rows][32 k]
    __shared__ ushort Bs[4096];   // [128 n][32 k]
    int tid = threadIdx.x;
    int l = tid & 63, w = tid >> 6;
    int i0 = blockIdx.x * 128;
    int c0 = w * 64 + l, c1 = c0 + 256;
    int rA0 = c0 >> 2, sA0 = (c0 & 3) * 8;
    int rA1 = c1 >> 2, sA1 = (c1 & 3) * 8;
    int g0 = i0 + rA0; if (g0 >= M) g0 = M - 1;
    int g1 = i0 + rA1; if (g1 >= M) g1 = M - 1;
    int lm = l & 15, lq = l >> 4;

    floatx4 acc[2][8];
    #pragma unroll
    for (int rt = 0; rt < 2; rt++)
        #pragma unroll
        for (int ct = 0; ct < 8; ct++) acc[rt][ct] = (floatx4){0.f, 0.f, 0.f, 0.f};

    for (int kt = 0; kt < 8; ++kt) {
        const ushort* Asrc = (kt < 4) ? Alo : Ahi;
        int kb = (kt & 3) * 32;
        async16(Asrc + (size_t)g0 * 128 + kb + sA0, As + w * 512);
        async16(Asrc + (size_t)g1 * 128 + kb + sA1, As + 2048 + w * 512);
        async16(WT + rA0 * 256 + kt * 32 + sA0, Bs + w * 512);
        async16(WT + rA1 * 256 + kt * 32 + sA1, Bs + 2048 + w * 512);
        __syncthreads();
        bf16x8 a0 = *(const bf16x8*)(As + (w * 32 + lm) * 32 + lq * 8);
        bf16x8 a1 = *(const bf16x8*)(As + (w * 32 + 16 + lm) * 32 + lq * 8);
        #pragma unroll
        for (int ct = 0; ct < 8; ++ct) {
            bf16x8 b = *(const bf16x8*)(Bs + (ct * 16 + lm) * 32 + lq * 8);
            acc[0][ct] = __builtin_amdgcn_mfma_f32_16x16x32_bf16(a0, b, acc[0][ct], 0, 0, 0);
            acc[1][ct] = __builtin_amdgcn_mfma_f32_16x16x32_bf16(a1, b, acc[1][ct], 0, 0, 0);
        }
        __syncthreads();
    }

    float bv[8];
    #pragma unroll
    for (int ct = 0; ct < 8; ++ct) bv[ct] = bias[ct * 16 + lm];
    #pragma unroll
    for (int rt = 0; rt < 2; ++rt)
        #pragma unroll
        for (int ct = 0; ct < 8; ++ct)
            #pragma unroll
            for (int r = 0; r < 4; ++r) {
                int grow = i0 + w * 32 + rt * 16 + lq * 4 + r;
                if (grow < M)
                    out[(size_t)grow * 128 + ct * 16 + lm] =
                        f2bf(fmaxf(acc[rt][ct][r] + bv[ct], 0.f));
            }
}

// ============================ fused edge MLP ============================
// A (128 edges x [x[qs]|x[qd]] = 64 KB) staged upfront with 16 async16/thread
// (XOR-swizzled 16B segs), ONE barrier. W1 B-frags load global->reg (L1-hot).
// Barrier-free K-loop. Stage 2 via Hs/W2s MFMA as before.
#define HSTR 136

__global__ __launch_bounds__(256) void k_mlp(
    const ushort* __restrict__ x16, const int* __restrict__ qs, const int* __restrict__ qd,
    const ushort* __restrict__ W1T, const float* __restrict__ b1,
    const ushort* __restrict__ W2T, const float* __restrict__ b2,
    float* __restrict__ out, int Eq) {
    __shared__ union {
        ushort As[128 * 256];   // 64 KB: [row 128][seg 32 x 16B], seg XOR-swizzled
        struct { ushort Hs[128 * HSTR]; ushort W2s[16 * HSTR]; } s2;
    } sm;
    __shared__ int Ns[256];     // [0..127]=qs, [128..255]=qd
    int tid = threadIdx.x;
    int l = tid & 63, w = tid >> 6;
    int lm = l & 15, lq = l >> 4;
    int e0 = blockIdx.x * 128;
    {
        int r = tid & 127;
        int e = e0 + r; if (e >= Eq) e = Eq - 1;
        Ns[tid] = (tid < 128) ? qs[e] : qd[e];
    }
    __syncthreads();

    // stage full A: call i, lane l -> flat slot f = i*256 + w*64 + l
    // LDS[r][sg] = x[node(ep,r)][(sg&15) ^ (r&15)]  (ep = sg>>4)
    #pragma unroll
    for (int i = 0; i < 16; ++i) {
        int f = i * 256 + w * 64 + l;
        int r = f >> 5;
        int sg = f & 31;
        int node = Ns[((sg >> 4) << 7) | r];
        const ushort* g = x16 + (size_t)node * 128 + (((sg & 15) ^ (r & 15)) << 3);
        async16(g, sm.As + (i * 256 + w * 64) * 8);
    }
    __syncthreads();

    floatx4 acc[2][8];
    #pragma unroll
    for (int rt = 0; rt < 2; rt++)
        #pragma unroll
        for (int ct = 0; ct < 8; ct++) acc[rt][ct] = (floatx4){0.f, 0.f, 0.f, 0.f};

    int r0 = w * 32 + lm, r1 = r0 + 16;   // r0&15 == r1&15 == lm
    #pragma unroll 2
    for (int kt = 0; kt < 8; ++kt) {
        int sgl = kt * 4 + lq;            // global seg 0..31
        int ep = sgl >> 4, si = sgl & 15;
        int seg = (ep << 4) | (si ^ lm);
        bf16x8 a0 = *(const bf16x8*)(sm.As + r0 * 256 + seg * 8);
        bf16x8 a1 = *(const bf16x8*)(sm.As + r1 * 256 + seg * 8);
        #pragma unroll
        for (int ct = 0; ct < 8; ++ct) {
            bf16x8 b = *(const bf16x8*)(W1T + (ct * 16 + lm) * 256 + kt * 32 + lq * 8);
            acc[0][ct] = __builtin_amdgcn_mfma_f32_16x16x32_bf16(a0, b, acc[0][ct], 0, 0, 0);
            acc[1][ct] = __builtin_amdgcn_mfma_f32_16x16x32_bf16(a1, b, acc[1][ct], 0, 0, 0);
        }
    }

    // stage-1 epilogue: h = relu(acc + b1) -> Hs (bf16); stage W2 -> W2s
    float b1v[8];
    #pragma unroll
    for (int ct = 0; ct < 8; ++ct) b1v[ct] = b1[ct * 16 + lm];
    __syncthreads();   // all waves done reading As before union reuse
    #pragma unroll
    for (int rt = 0; rt < 2; ++rt)
        #pragma unroll
        for (int ct = 0; ct < 8; ++ct)
            #pragma unroll
            for (int r = 0; r < 4; ++r) {
                int row = w * 32 + rt * 16 + lq * 4 + r;
                int col = ct * 16 + lm;
                sm.s2.Hs[row * HSTR + col] = f2bf(fmaxf(acc[rt][ct][r] + b1v[ct], 0.f));
            }
    {
        int n = tid >> 4, kc = (tid & 15) * 8;
        #pragma unroll
        for (int j = 0; j < 8; ++j)
            sm.s2.W2s[n * HSTR + kc + j] = W2T[n * 128 + kc + j];
    }
    __syncthreads();

    // stage 2: logits = h @ W2 + b2 (MFMA, N=16 with cols 8..15 zero)
    floatx4 acc2[2];
    acc2[0] = (floatx4){0.f, 0.f, 0.f, 0.f};
    acc2[1] = (floatx4){0.f, 0.f, 0.f, 0.f};
    #pragma unroll
    for (int ks = 0; ks < 4; ++ks) {
        bf16x8 bw = *(const bf16x8*)(sm.s2.W2s + lm * HSTR + ks * 32 + lq * 8);
        bf16x8 h0 = *(const bf16x8*)(sm.s2.Hs + (w * 32 + lm) * HSTR + ks * 32 + lq * 8);
        bf16x8 h1 = *(const bf16x8*)(sm.s2.Hs + (w * 32 + 16 + lm) * HSTR + ks * 32 + lq * 8);
        acc2[0] = __builtin_amdgcn_mfma_f32_16x16x32_bf16(h0, bw, acc2[0], 0, 0, 0);
        acc2[1] = __builtin_amdgcn_mfma_f32_16x16x32_bf16(h1, bw, acc2[1], 0, 0, 0);
    }
    if (lm < 8) {
        float bb = b2[lm];
        #pragma unroll
        for (int rt = 0; rt < 2; ++rt)
            #pragma unroll
            for (int r = 0; r < 4; ++r) {
                int eg = e0 + w * 32 + rt * 16 + lq * 4 + r;
                if (eg < Eq) out[(size_t)eg * 8 + lm] = acc2[rt][r] + bb;
            }
    }
}

// ============================ launch ============================

extern "C" void kernel_launch(void* const* d_in, const int* in_sizes, int n_in,
                              void* d_out, int out_size, void* d_ws, size_t ws_size,
                              hipStream_t stream) {
    const float* node_emb = (const float*)d_in[0];
    const float* Wl0 = (const float*)d_in[1];
    const float* bl0 = (const float*)d_in[2];
    const float* Wr0 = (const float*)d_in[3];
    const float* Wl1 = (const float*)d_in[4];
    const float* bl1 = (const float*)d_in[5];
    const float* Wr1 = (const float*)d_in[6];
    const float* W1  = (const float*)d_in[7];
    const float* b1  = (const float*)d_in[8];
    const float* W2  = (const float*)d_in[9];
    const float* b2  = (const float*)d_in[10];
    const int* eidx  = (const int*)d_in[11];
    const int* eq    = (const int*)d_in[12];

    int N  = in_sizes[0] / HID;
    int E  = in_sizes[11] / 2;
    int Eq = in_sizes[12] / 2;
    const int* srcp = eidx;
    const int* dstp = eidx + E;
    const int* qs = eq;
    const int* qd = eq + Eq;
    float* outp = (float*)d_out;
    int NB = (N + NODES_PER_BIN - 1) >> SH;

    char* ws = (char*)d_ws;
    size_t off = 0;
    auto take = [&](size_t bytes) -> char* {
        char* p = ws + off;
        off += (bytes + 255) & ~(size_t)255;
        return p;
    };
    int* binc       = (int*)take(256 * 4);
    int* bin_start  = (int*)take(257 * 4);
    int* bin_cursor = (int*)take(256 * 4);
    int* rowptr     = (int*)take((size_t)(N + 1) * 4);
    int* csr        = (int*)take((size_t)E * 4);
    // mean16 (25.6MB) aliases ebuf (6.4MB): ebuf dead before first agg write
    char* meanreg   = take((size_t)N * HID * 2);
    uint* ebuf      = (uint*)meanreg;
    ushort* mean16  = (ushort*)meanreg;
    ushort* x0_16   = (ushort*)take((size_t)N * HID * 2);   // also xb16
    ushort* xa16    = (ushort*)take((size_t)N * HID * 2);
    ushort* xb16    = x0_16;
    ushort* WlrT0   = (ushort*)take(32768 * 2);
    ushort* WlrT1   = (ushort*)take(32768 * 2);
    ushort* W1T     = (ushort*)take(32768 * 2);
    ushort* W2T     = (ushort*)take(2048 * 2);

    hipMemsetAsync(binc, 0, 256 * 4, stream);

    k_hist<<<256, 256, 0, stream>>>(dstp, E, binc);
    k_binscan<<<1, 256, 0, stream>>>(binc, bin_start, bin_cursor, E);
    int pb = (E + 2047) / 2048;
    k_part<<<pb, 256, 0, stream>>>(srcp, dstp, E, bin_cursor, ebuf);
    k_csr<<<NB, 256, 0, stream>>>(ebuf, bin_start, rowptr, csr, N, E, NB);

    int n4 = N * HID / 4;
    const int TB = 256;
    k_cvt<<<(n4 + TB - 1) / TB, TB, 0, stream>>>(node_emb, x0_16, n4);
    k_prepw<<<392, 256, 0, stream>>>(Wl0, Wr0, Wl1, Wr1, W1, W2, WlrT0, WlrT1, W1T, W2T);

    int ag = (N + 15) / 16;
    int mg = (N + 127) / 128;
    k_agg4<<<ag, 256, 0, stream>>>(x0_16, rowptr, csr, mean16, N);
    k_gemm16<<<mg, 256, 0, stream>>>(mean16, x0_16, WlrT0, bl0, xa16, N);
    k_agg4<<<ag, 256, 0, stream>>>(xa16, rowptr, csr, mean16, N);
    k_gemm16<<<mg, 256, 0, stream>>>(mean16, xa16, WlrT1, bl1, xb16, N);

    int eg = (Eq + 127) / 128;
    k_mlp<<<eg, 256, 0, stream>>>(xb16, qs, qd, W1T, b1, W2T, b2, outp, Eq);
}

// Round 8
// 383.626 us; speedup vs baseline: 1.2682x; 1.2682x over previous
//
#include <hip/hip_runtime.h>
#include <hip/hip_bf16.h>
#include <cstdint>
#include <cstddef>

#define HID 128
#define SH 9                 // 512 nodes per bin
#define NODES_PER_BIN 512

typedef __attribute__((ext_vector_type(8))) __bf16 bf16x8;
typedef __attribute__((ext_vector_type(4))) float floatx4;

__device__ __forceinline__ ushort f2bf(float f) {
    uint u = __float_as_uint(f);
    u += 0x7fff + ((u >> 16) & 1);          // round-to-nearest-even
    return (ushort)(u >> 16);
}
__device__ __forceinline__ float bf2f(uint h) { return __uint_as_float(h << 16); }
__device__ __forceinline__ uint pack2(float a, float b) {
    return (uint)f2bf(a) | ((uint)f2bf(b) << 16);
}

// async global->LDS, 16B per lane; LDS dest is wave-uniform base + lane*16
__device__ __forceinline__ void async16(const ushort* g, ushort* l) {
    __builtin_amdgcn_global_load_lds(
        (const __attribute__((address_space(1))) uint*)g,
        (__attribute__((address_space(3))) uint*)l, 16, 0, 0);
}

// ============================ binned CSR build ============================

__global__ void k_hist(const int* __restrict__ dst, int E, int* __restrict__ binc) {
    __shared__ int h[256];
    int t = threadIdx.x;
    h[t] = 0;
    __syncthreads();
    for (int e = blockIdx.x * 256 + t; e < E; e += gridDim.x * 256)
        atomicAdd(&h[dst[e] >> SH], 1);
    __syncthreads();
    if (h[t]) atomicAdd(&binc[t], h[t]);
}

__global__ void k_binscan(const int* __restrict__ binc, int* __restrict__ bin_start,
                          int* __restrict__ bin_cursor, int E) {
    __shared__ int s[256];
    int t = threadIdx.x;
    int c = binc[t];
    s[t] = c;
    __syncthreads();
    #pragma unroll
    for (int off = 1; off < 256; off <<= 1) {
        int add = (t >= off) ? s[t - off] : 0;
        __syncthreads();
        s[t] += add;
        __syncthreads();
    }
    int excl = s[t] - c;
    bin_start[t] = excl;
    bin_cursor[t] = excl;
    if (t == 255) bin_start[256] = E;
}

// 2048 edges/block: in-LDS multi-split by bin, then coalesced bin-grouped writes.
// packed word = (d & 511) << 23 | src   (requires src < 2^23)
__global__ __launch_bounds__(256) void k_part(
    const int* __restrict__ src, const int* __restrict__ dst, int E,
    int* __restrict__ bin_cursor, uint* __restrict__ ebuf) {
    __shared__ int h[256];
    __shared__ int sc[256];
    __shared__ int rk[256];
    __shared__ int gb[256];
    __shared__ uint2 ro[2048];   // (d, packed)
    int t = threadIdx.x;
    int base = blockIdx.x * 2048;
    h[t] = 0;
    __syncthreads();
    int dd[8], ss[8];
    bool ok[8];
    #pragma unroll
    for (int k = 0; k < 8; ++k) {
        int e = base + k * 256 + t;
        ok[k] = e < E;
        if (ok[k]) {
            dd[k] = dst[e];
            ss[k] = src[e];
            atomicAdd(&h[dd[k] >> SH], 1);
        }
    }
    __syncthreads();
    sc[t] = h[t];
    __syncthreads();
    #pragma unroll
    for (int off = 1; off < 256; off <<= 1) {
        int add = (t >= off) ? sc[t - off] : 0;
        __syncthreads();
        sc[t] += add;
        __syncthreads();
    }
    rk[t] = sc[t] - h[t];           // exclusive
    {
        int c = h[t];
        if (c > 0) gb[t] = atomicAdd(&bin_cursor[t], c);
    }
    __syncthreads();
    #pragma unroll
    for (int k = 0; k < 8; ++k) {
        if (ok[k]) {
            int bin = dd[k] >> SH;
            int r = atomicAdd(&rk[bin], 1);
            ro[r] = make_uint2((uint)dd[k],
                               ((uint)(dd[k] & (NODES_PER_BIN - 1)) << 23) | (uint)ss[k]);
        }
    }
    __syncthreads();
    int nv = sc[255];
    for (int i = t; i < nv; i += 256) {
        uint2 pr = ro[i];
        int bin = (int)(pr.x >> SH);
        int excl = sc[bin] - h[bin];
        ebuf[gb[bin] + (i - excl)] = pr.y;
    }
}

// one block per bin: exact CSR for 512 nodes via LDS count+scan
__global__ __launch_bounds__(256) void k_csr(
    const uint* __restrict__ ebuf, const int* __restrict__ bin_start,
    int* __restrict__ rowptr, int* __restrict__ csr, int N, int E, int NB) {
    __shared__ int cnt[512];
    __shared__ int p[256];
    __shared__ int excl[512];
    int t = threadIdx.x;
    int b = blockIdx.x;
    int d0 = b << SH;
    int ebase = bin_start[b], eend = bin_start[b + 1];
    cnt[t] = 0; cnt[t + 256] = 0;
    __syncthreads();
    for (int e = ebase + t; e < eend; e += 256)
        atomicAdd(&cnt[ebuf[e] >> 23], 1);
    __syncthreads();
    p[t] = cnt[2 * t] + cnt[2 * t + 1];
    __syncthreads();
    #pragma unroll
    for (int off = 1; off < 256; off <<= 1) {
        int add = (t >= off) ? p[t - off] : 0;
        __syncthreads();
        p[t] += add;
        __syncthreads();
    }
    int e0 = (t == 0) ? 0 : p[t - 1];
    excl[2 * t] = e0;
    excl[2 * t + 1] = e0 + cnt[2 * t];
    __syncthreads();
    #pragma unroll
    for (int i = t; i < 512; i += 256) {
        int node = d0 + i;
        if (node < N) rowptr[node] = ebase + excl[i];
    }
    if (b == NB - 1 && t == 0) rowptr[N] = E;
    __syncthreads();
    for (int e = ebase + t; e < eend; e += 256) {
        uint w = ebuf[e];
        int r = atomicAdd(&excl[w >> 23], 1);
        csr[ebase + r] = (int)(w & 0x7FFFFFu);
    }
}

// ============================ prep: fp32 -> bf16, weight transposes ============

__global__ void k_cvt(const float* __restrict__ in, ushort* __restrict__ out, int n4) {
    int i = blockIdx.x * blockDim.x + threadIdx.x;
    if (i < n4) {
        float4 v = ((const float4*)in)[i];
        ((uint2*)out)[i] = make_uint2(pack2(v.x, v.y), pack2(v.z, v.w));
    }
}

__global__ void k_prepw(const float* __restrict__ Wl0, const float* __restrict__ Wr0,
                        const float* __restrict__ Wl1, const float* __restrict__ Wr1,
                        const float* __restrict__ W1,  const float* __restrict__ W2,
                        ushort* __restrict__ WlrT0, ushort* __restrict__ WlrT1,
                        ushort* __restrict__ W1T,   ushort* __restrict__ W2T) {
    int idx = blockIdx.x * 256 + threadIdx.x;
    if (idx < 32768) {
        int n = idx >> 8, k = idx & 255;
        float v = (k < 128) ? Wl0[k * 128 + n] : Wr0[(k - 128) * 128 + n];
        WlrT0[n * 256 + k] = f2bf(v);
    } else if (idx < 65536) {
        int t = idx - 32768; int n = t >> 8, k = t & 255;
        float v = (k < 128) ? Wl1[k * 128 + n] : Wr1[(k - 128) * 128 + n];
        WlrT1[n * 256 + k] = f2bf(v);
    } else if (idx < 98304) {
        int t = idx - 65536; int n = t >> 8, k = t & 255;
        W1T[n * 256 + k] = f2bf(W1[k * 128 + n]);
    } else if (idx < 100352) {
        int t = idx - 98304; int n = t >> 7, k = t & 127;
        W2T[n * 128 + k] = (n < 8) ? f2bf(W2[k * 8 + n]) : (ushort)0;
    }
}

// ============================ mean aggregation (bf16 in/out) ============================
// 16 lanes per node (quarter-wave owns the full 256 B row via uint4/lane);
// edge loop unrolled x8 -> 8 row-gathers in flight per lane.
__global__ __launch_bounds__(256) void k_agg4(const ushort* __restrict__ x,
                                              const int* __restrict__ rowptr,
                                              const int* __restrict__ csr,
                                              ushort* __restrict__ mean, int N) {
    int node = blockIdx.x * 16 + (threadIdx.x >> 4);
    if (node >= N) return;
    int u = threadIdx.x & 15;
    int b = rowptr[node], e = rowptr[node + 1];
    const uint4* xv = (const uint4*)x;      // row = 16 uint4
    float a0=0.f,a1=0.f,a2=0.f,a3=0.f,a4=0.f,a5=0.f,a6=0.f,a7=0.f;
    auto accum = [&](uint4 v) {
        a0 += __uint_as_float(v.x << 16);
        a1 += __uint_as_float(v.x & 0xffff0000u);
        a2 += __uint_as_float(v.y << 16);
        a3 += __uint_as_float(v.y & 0xffff0000u);
        a4 += __uint_as_float(v.z << 16);
        a5 += __uint_as_float(v.z & 0xffff0000u);
        a6 += __uint_as_float(v.w << 16);
        a7 += __uint_as_float(v.w & 0xffff0000u);
    };
    int j = b;
    for (; j + 7 < e; j += 8) {
        int s0 = csr[j],   s1 = csr[j+1], s2 = csr[j+2], s3 = csr[j+3];
        int s4 = csr[j+4], s5 = csr[j+5], s6 = csr[j+6], s7 = csr[j+7];
        uint4 v0 = xv[(size_t)s0 * 16 + u];
        uint4 v1 = xv[(size_t)s1 * 16 + u];
        uint4 v2 = xv[(size_t)s2 * 16 + u];
        uint4 v3 = xv[(size_t)s3 * 16 + u];
        uint4 v4 = xv[(size_t)s4 * 16 + u];
        uint4 v5 = xv[(size_t)s5 * 16 + u];
        uint4 v6 = xv[(size_t)s6 * 16 + u];
        uint4 v7 = xv[(size_t)s7 * 16 + u];
        accum(v0); accum(v1); accum(v2); accum(v3);
        accum(v4); accum(v5); accum(v6); accum(v7);
    }
    for (; j + 3 < e; j += 4) {
        int s0 = csr[j], s1 = csr[j+1], s2 = csr[j+2], s3 = csr[j+3];
        uint4 v0 = xv[(size_t)s0 * 16 + u];
        uint4 v1 = xv[(size_t)s1 * 16 + u];
        uint4 v2 = xv[(size_t)s2 * 16 + u];
        uint4 v3 = xv[(size_t)s3 * 16 + u];
        accum(v0); accum(v1); accum(v2); accum(v3);
    }
    for (; j < e; ++j) accum(xv[(size_t)csr[j] * 16 + u]);
    float inv = 1.f / fmaxf((float)(e - b), 1.f);
    uint4 o;
    o.x = pack2(a0 * inv, a1 * inv);
    o.y = pack2(a2 * inv, a3 * inv);
    o.z = pack2(a4 * inv, a5 * inv);
    o.w = pack2(a6 * inv, a7 * inv);
    ((uint4*)mean)[(size_t)node * 16 + u] = o;
}

// ============================ layer GEMM (bf16 MFMA) ============================
__global__ __launch_bounds__(256) void k_gemm16(
    const ushort* __restrict__ Alo, const ushort* __restrict__ Ahi,
    const ushort* __restrict__ WT, const float* __restrict__ bias,
    ushort* __restrict__ out, int M) {
    __shared__ ushort As[4096];   // [128 rows][32 k]
    __shared__ ushort Bs[4096];   // [128 n][32 k]
    int tid = threadIdx.x;
    int l = tid & 63, w = tid >> 6;
    int i0 = blockIdx.x * 128;
    int c0 = w * 64 + l, c1 = c0 + 256;
    int rA0 = c0 >> 2, sA0 = (c0 & 3) * 8;
    int rA1 = c1 >> 2, sA1 = (c1 & 3) * 8;
    int g0 = i0 + rA0; if (g0 >= M) g0 = M - 1;
    int g1 = i0 + rA1; if (g1 >= M) g1 = M - 1;
    int lm = l & 15, lq = l >> 4;

    floatx4 acc[2][8];
    #pragma unroll
    for (int rt = 0; rt < 2; rt++)
        #pragma unroll
        for (int ct = 0; ct < 8; ct++) acc[rt][ct] = (floatx4){0.f, 0.f, 0.f, 0.f};

    for (int kt = 0; kt < 8; ++kt) {
        const ushort* Asrc = (kt < 4) ? Alo : Ahi;
        int kb = (kt & 3) * 32;
        async16(Asrc + (size_t)g0 * 128 + kb + sA0, As + w * 512);
        async16(Asrc + (size_t)g1 * 128 + kb + sA1, As + 2048 + w * 512);
        async16(WT + rA0 * 256 + kt * 32 + sA0, Bs + w * 512);
        async16(WT + rA1 * 256 + kt * 32 + sA1, Bs + 2048 + w * 512);
        __syncthreads();
        bf16x8 a0 = *(const bf16x8*)(As + (w * 32 + lm) * 32 + lq * 8);
        bf16x8 a1 = *(const bf16x8*)(As + (w * 32 + 16 + lm) * 32 + lq * 8);
        #pragma unroll
        for (int ct = 0; ct < 8; ++ct) {
            bf16x8 b = *(const bf16x8*)(Bs + (ct * 16 + lm) * 32 + lq * 8);
            acc[0][ct] = __builtin_amdgcn_mfma_f32_16x16x32_bf16(a0, b, acc[0][ct], 0, 0, 0);
            acc[1][ct] = __builtin_amdgcn_mfma_f32_16x16x32_bf16(a1, b, acc[1][ct], 0, 0, 0);
        }
        __syncthreads();
    }

    float bv[8];
    #pragma unroll
    for (int ct = 0; ct < 8; ++ct) bv[ct] = bias[ct * 16 + lm];
    #pragma unroll
    for (int rt = 0; rt < 2; ++rt)
        #pragma unroll
        for (int ct = 0; ct < 8; ++ct)
            #pragma unroll
            for (int r = 0; r < 4; ++r) {
                int grow = i0 + w * 32 + rt * 16 + lq * 4 + r;
                if (grow < M)
                    out[(size_t)grow * 128 + ct * 16 + lm] =
                        f2bf(fmaxf(acc[rt][ct][r] + bv[ct], 0.f));
            }
}

// ============================ fused edge MLP (bf16 MFMA both stages) ============
// R5 structure + (a) double-kt supersteps: 8 async16/thread in flight, barriers
// 16 -> 8; (b) XOR seg-swizzle applied to the GLOBAL source (LDS dest stays
// lane-contiguous so async16 remains legal) -> frag ds_read_b128 conflicts 8->4 way.
#define HSTR 136

__global__ __launch_bounds__(256) void k_mlp(
    const ushort* __restrict__ x16, const int* __restrict__ qs, const int* __restrict__ qd,
    const ushort* __restrict__ W1T, const float* __restrict__ b1,
    const ushort* __restrict__ W2T, const float* __restrict__ b2,
    float* __restrict__ out, int Eq) {
    __shared__ union {
        struct { ushort As[8192]; ushort Bs[8192]; } s1;             // 32 KB
        struct { ushort Hs[128 * HSTR]; ushort W2s[16 * HSTR]; } s2; // ~39 KB
    } sm;
    __shared__ int Ns[256];
    int tid = threadIdx.x;
    int l = tid & 63, w = tid >> 6;
    int lm = l & 15, lq = l >> 4;
    int e0 = blockIdx.x * 128;
    {
        int r = tid & 127;
        int e = e0 + r; if (e >= Eq) e = Eq - 1;
        Ns[tid] = (tid < 128) ? qs[e] : qd[e];
    }
    __syncthreads();

    int c0 = w * 64 + l, c1 = c0 + 256;
    int rA0 = c0 >> 2, sw0 = ((c0 & 3) ^ (rA0 & 3)) * 8;   // swizzled global seg
    int rA1 = c1 >> 2, sw1 = ((c1 & 3) ^ (rA1 & 3)) * 8;
    ushort* As = sm.s1.As;
    ushort* Bs = sm.s1.Bs;
    int xs = (lq ^ (lm & 3)) * 8;   // swizzled seg for frag reads (row&3 == lm&3)

    floatx4 acc[2][8];
    #pragma unroll
    for (int rt = 0; rt < 2; rt++)
        #pragma unroll
        for (int ct = 0; ct < 8; ct++) acc[rt][ct] = (floatx4){0.f, 0.f, 0.f, 0.f};

    for (int st = 0; st < 4; ++st) {
        const int* Nbase = (st < 2) ? Ns : (Ns + 128);
        int n0 = Nbase[rA0], n1 = Nbase[rA1];
        int kt0 = 2 * st, kt1 = 2 * st + 1;
        int kb0 = (kt0 & 3) * 32, kb1 = (kt1 & 3) * 32;
        async16(x16 + (size_t)n0 * 128 + kb0 + sw0, As + w * 512);
        async16(x16 + (size_t)n1 * 128 + kb0 + sw1, As + 2048 + w * 512);
        async16(x16 + (size_t)n0 * 128 + kb1 + sw0, As + 4096 + w * 512);
        async16(x16 + (size_t)n1 * 128 + kb1 + sw1, As + 4096 + 2048 + w * 512);
        async16(W1T + rA0 * 256 + kt0 * 32 + sw0, Bs + w * 512);
        async16(W1T + rA1 * 256 + kt0 * 32 + sw1, Bs + 2048 + w * 512);
        async16(W1T + rA0 * 256 + kt1 * 32 + sw0, Bs + 4096 + w * 512);
        async16(W1T + rA1 * 256 + kt1 * 32 + sw1, Bs + 4096 + 2048 + w * 512);
        __syncthreads();
        #pragma unroll
        for (int h = 0; h < 2; ++h) {
            bf16x8 a0 = *(const bf16x8*)(As + h * 4096 + (w * 32 + lm) * 32 + xs);
            bf16x8 a1 = *(const bf16x8*)(As + h * 4096 + (w * 32 + 16 + lm) * 32 + xs);
            #pragma unroll
            for (int ct = 0; ct < 8; ++ct) {
                bf16x8 b = *(const bf16x8*)(Bs + h * 4096 + (ct * 16 + lm) * 32 + xs);
                acc[0][ct] = __builtin_amdgcn_mfma_f32_16x16x32_bf16(a0, b, acc[0][ct], 0, 0, 0);
                acc[1][ct] = __builtin_amdgcn_mfma_f32_16x16x32_bf16(a1, b, acc[1][ct], 0, 0, 0);
            }
        }
        __syncthreads();
    }

    // stage-1 epilogue: h = relu(acc + b1) -> Hs (bf16); stage W2 -> W2s
    float b1v[8];
    #pragma unroll
    for (int ct = 0; ct < 8; ++ct) b1v[ct] = b1[ct * 16 + lm];
    #pragma unroll
    for (int rt = 0; rt < 2; ++rt)
        #pragma unroll
        for (int ct = 0; ct < 8; ++ct)
            #pragma unroll
            for (int r = 0; r < 4; ++r) {
                int row = w * 32 + rt * 16 + lq * 4 + r;
                int col = ct * 16 + lm;
                sm.s2.Hs[row * HSTR + col] = f2bf(fmaxf(acc[rt][ct][r] + b1v[ct], 0.f));
            }
    {
        int n = tid >> 4, kc = (tid & 15) * 8;
        #pragma unroll
        for (int j = 0; j < 8; ++j)
            sm.s2.W2s[n * HSTR + kc + j] = W2T[n * 128 + kc + j];
    }
    __syncthreads();

    // stage 2: logits = h @ W2 + b2 (MFMA, N=16 with cols 8..15 zero)
    floatx4 acc2[2];
    acc2[0] = (floatx4){0.f, 0.f, 0.f, 0.f};
    acc2[1] = (floatx4){0.f, 0.f, 0.f, 0.f};
    #pragma unroll
    for (int ks = 0; ks < 4; ++ks) {
        bf16x8 bw = *(const bf16x8*)(sm.s2.W2s + lm * HSTR + ks * 32 + lq * 8);
        bf16x8 h0 = *(const bf16x8*)(sm.s2.Hs + (w * 32 + lm) * HSTR + ks * 32 + lq * 8);
        bf16x8 h1 = *(const bf16x8*)(sm.s2.Hs + (w * 32 + 16 + lm) * HSTR + ks * 32 + lq * 8);
        acc2[0] = __builtin_amdgcn_mfma_f32_16x16x32_bf16(h0, bw, acc2[0], 0, 0, 0);
        acc2[1] = __builtin_amdgcn_mfma_f32_16x16x32_bf16(h1, bw, acc2[1], 0, 0, 0);
    }
    if (lm < 8) {
        float bb = b2[lm];
        #pragma unroll
        for (int rt = 0; rt < 2; ++rt)
            #pragma unroll
            for (int r = 0; r < 4; ++r) {
                int eg = e0 + w * 32 + rt * 16 + lq * 4 + r;
                if (eg < Eq) out[(size_t)eg * 8 + lm] = acc2[rt][r] + bb;
            }
    }
}

// ============================ launch ============================

extern "C" void kernel_launch(void* const* d_in, const int* in_sizes, int n_in,
                              void* d_out, int out_size, void* d_ws, size_t ws_size,
                              hipStream_t stream) {
    const float* node_emb = (const float*)d_in[0];
    const float* Wl0 = (const float*)d_in[1];
    const float* bl0 = (const float*)d_in[2];
    const float* Wr0 = (const float*)d_in[3];
    const float* Wl1 = (const float*)d_in[4];
    const float* bl1 = (const float*)d_in[5];
    const float* Wr1 = (const float*)d_in[6];
    const float* W1  = (const float*)d_in[7];
    const float* b1  = (const float*)d_in[8];
    const float* W2  = (const float*)d_in[9];
    const float* b2  = (const float*)d_in[10];
    const int* eidx  = (const int*)d_in[11];
    const int* eq    = (const int*)d_in[12];

    int N  = in_sizes[0] / HID;
    int E  = in_sizes[11] / 2;
    int Eq = in_sizes[12] / 2;
    const int* srcp = eidx;
    const int* dstp = eidx + E;
    const int* qs = eq;
    const int* qd = eq + Eq;
    float* outp = (float*)d_out;
    int NB = (N + NODES_PER_BIN - 1) >> SH;

    char* ws = (char*)d_ws;
    size_t off = 0;
    auto take = [&](size_t bytes) -> char* {
        char* p = ws + off;
        off += (bytes + 255) & ~(size_t)255;
        return p;
    };
    int* binc       = (int*)take(256 * 4);
    int* bin_start  = (int*)take(257 * 4);
    int* bin_cursor = (int*)take(256 * 4);
    int* rowptr     = (int*)take((size_t)(N + 1) * 4);
    int* csr        = (int*)take((size_t)E * 4);
    // mean16 (25.6MB) aliases ebuf (6.4MB): ebuf dead before first agg write
    char* meanreg   = take((size_t)N * HID * 2);
    uint* ebuf      = (uint*)meanreg;
    ushort* mean16  = (ushort*)meanreg;
    ushort* x0_16   = (ushort*)take((size_t)N * HID * 2);   // also xb16
    ushort* xa16    = (ushort*)take((size_t)N * HID * 2);
    ushort* xb16    = x0_16;
    ushort* WlrT0   = (ushort*)take(32768 * 2);
    ushort* WlrT1   = (ushort*)take(32768 * 2);
    ushort* W1T     = (ushort*)take(32768 * 2);
    ushort* W2T     = (ushort*)take(2048 * 2);

    hipMemsetAsync(binc, 0, 256 * 4, stream);

    k_hist<<<256, 256, 0, stream>>>(dstp, E, binc);
    k_binscan<<<1, 256, 0, stream>>>(binc, bin_start, bin_cursor, E);
    int pb = (E + 2047) / 2048;
    k_part<<<pb, 256, 0, stream>>>(srcp, dstp, E, bin_cursor, ebuf);
    k_csr<<<NB, 256, 0, stream>>>(ebuf, bin_start, rowptr, csr, N, E, NB);

    int n4 = N * HID / 4;
    const int TB = 256;
    k_cvt<<<(n4 + TB - 1) / TB, TB, 0, stream>>>(node_emb, x0_16, n4);
    k_prepw<<<392, 256, 0, stream>>>(Wl0, Wr0, Wl1, Wr1, W1, W2, WlrT0, WlrT1, W1T, W2T);

    int ag = (N + 15) / 16;
    int mg = (N + 127) / 128;
    k_agg4<<<ag, 256, 0, stream>>>(x0_16, rowptr, csr, mean16, N);
    k_gemm16<<<mg, 256, 0, stream>>>(mean16, x0_16, WlrT0, bl0, xa16, N);
    k_agg4<<<ag, 256, 0, stream>>>(xa16, rowptr, csr, mean16, N);
    k_gemm16<<<mg, 256, 0, stream>>>(mean16, xa16, WlrT1, bl1, xb16, N);

    int eg = (Eq + 127) / 128;
    k_mlp<<<eg, 256, 0, stream>>>(xb16, qs, qd, W1T, b1, W2T, b2, outp, Eq);
}